// Round 5
// baseline (96.105 us; speedup 1.0000x reference)
//
#include <hip/hip_runtime.h>

#define SEQ   2048
#define DHEAD 64
#define QBLK  128
#define KVBLK 64
#define NT    (SEQ / KVBLK)      // 32 tiles
#define NI    (NT / 2)           // 16 tiles per KV-group
#define TILE_H (KVBLK * DHEAD)   // halves per K or V tile (4096 = 8KB)

typedef _Float16 half4v __attribute__((ext_vector_type(4)));
typedef _Float16 half8  __attribute__((ext_vector_type(8)));
typedef float    f32x16 __attribute__((ext_vector_type(16)));
typedef unsigned u32;

__device__ __forceinline__ u32 cvt2(float x, float y) {
    return __builtin_bit_cast(u32, __builtin_amdgcn_cvt_pkrtz(x, y));
}

__device__ __forceinline__ half8 pack8(float4 a, float4 b) {
    union { u32 w[4]; half8 h; } r;
    r.w[0] = cvt2(a.x, a.y);
    r.w[1] = cvt2(a.z, a.w);
    r.w[2] = cvt2(b.x, b.y);
    r.w[3] = cvt2(b.z, b.w);
    return r.h;
}

__device__ __forceinline__ float fexp2(float x) {
#if __has_builtin(__builtin_amdgcn_exp2f)
    return __builtin_amdgcn_exp2f(x);
#else
    return exp2f(x);
#endif
}

__global__ __launch_bounds__(512, 4)
void fattn_fwd(const float* __restrict__ Qg, const float* __restrict__ Kg,
               const float* __restrict__ Vg, float* __restrict__ Og)
{
    // [group][buf][K=0/V=1][tile]  = 64 KB total; merge buffer reuses this space
    __shared__ __align__(16) _Float16 smem[2][2][2][TILE_H];

    const int tid  = threadIdx.x;
    const int wave = tid >> 6;
    const int lane = tid & 63;
    const int lq   = lane & 31;   // q fragment index
    const int h    = lane >> 5;   // k-half of the wave
    const int g    = wave >> 2;   // KV parity group
    const int wv   = wave & 3;    // q sub-tile
    const int gtid = tid & 255;   // thread id within group

    // XCD-bijective swizzle: 512 blocks, 64 per XCD = 4 whole heads per XCD
    const int bid = blockIdx.x;
    const int swz = (bid & 7) * 64 + (bid >> 3);
    const int head = swz >> 4;                  // 16 q-blocks per head
    const int qb   = swz & 15;
    const size_t hbase = (size_t)head * (SEQ * DHEAD);
    const int q0 = qb * QBLK + wv * 32;

    // ---- Q B-fragments, pre-scaled by log2e/sqrt(D) (exp2-domain softmax) ----
    half8 qf[4];
    {
        const float* qrow = Qg + hbase + (size_t)(q0 + lq) * DHEAD;
        const float sc = 0.125f * 1.44269504088896f;
        #pragma unroll
        for (int ks = 0; ks < 4; ++ks) {
            float4 a = *(const float4*)(qrow + 16*ks + 8*h);
            float4 b = *(const float4*)(qrow + 16*ks + 8*h + 4);
            a.x*=sc; a.y*=sc; a.z*=sc; a.w*=sc;
            b.x*=sc; b.y*=sc; b.z*=sc; b.w*=sc;
            qf[ks] = pack8(a, b);
        }
    }

    f32x16 accO[2];
    #pragma unroll
    for (int dm = 0; dm < 2; ++dm)
        #pragma unroll
        for (int i = 0; i < 16; ++i) accO[dm][i] = 0.f;
    float m_run = -1e30f, l_run = 0.f;

    // ---- staging mapping: group-thread -> (kv row, 16-float d-group) ----
    const int srow = gtid >> 2;
    const int scg  = gtid & 3;
    // group g handles tiles T = 2i+g
    const float* kgg = Kg + hbase + (size_t)srow * DHEAD + scg * 16 + (size_t)g * TILE_H;
    const float* vgg = Vg + hbase + (size_t)srow * DHEAD + scg * 16 + (size_t)g * TILE_H;
    const int kwo0 = srow*64 + (((2*scg)   ^ (srow & 7)) << 3);
    const int kwo1 = srow*64 + (((2*scg+1) ^ (srow & 7)) << 3);
    const int kv4  = srow >> 2;
    const int psub = 16*(kv4>>2) + 8*(kv4&1) + 4*(scg>>1) + 2*((kv4>>1)&1) + (scg&1);
    const int vwo0 = psub*64 + (srow & 3)*16;

    _Float16* kst = &smem[g][0][0][0];   // buf stride = 2*TILE_H halves
    _Float16* vst = &smem[g][0][1][0];

    const int ksw = (lq & 7) << 3;
    const u32 vbase0 = (u32)(size_t)vst + (u32)lane * 8u;

    float4 kr0,kr1,kr2,kr3, vr0,vr1,vr2,vr3;
    #define LOADKV(I) {                                                        \
        const float* kp = kgg + (size_t)(I) * (2 * TILE_H);                     \
        const float* vp = vgg + (size_t)(I) * (2 * TILE_H);                     \
        kr0 = *(const float4*)(kp+0); kr1 = *(const float4*)(kp+4);             \
        kr2 = *(const float4*)(kp+8); kr3 = *(const float4*)(kp+12);            \
        vr0 = *(const float4*)(vp+0); vr1 = *(const float4*)(vp+4);             \
        vr2 = *(const float4*)(vp+8); vr3 = *(const float4*)(vp+12); }
    #define STAGE(B) {                                                         \
        *(half8*)&kst[(B)*(2*TILE_H) + kwo0]     = pack8(kr0, kr1);             \
        *(half8*)&kst[(B)*(2*TILE_H) + kwo1]     = pack8(kr2, kr3);             \
        *(half8*)&vst[(B)*(2*TILE_H) + vwo0]     = pack8(vr0, vr1);             \
        *(half8*)&vst[(B)*(2*TILE_H) + vwo0 + 8] = pack8(vr2, vr3); }

    LOADKV(0); STAGE(0);
    LOADKV(1);

    #pragma unroll 1
    for (int i = 0; i < NI; ++i) {
        const int cur = i & 1;
        __syncthreads();   // tile staged; prior readers of buf[cur^1] done
        if (i + 1 < NI) STAGE(cur ^ 1);
        if (i + 2 < NI) LOADKV(i + 2);

        // ---- S^T = K · Q^T : 2 kv m-tiles x 4 k-steps ----
        f32x16 sacc[2];
        __builtin_amdgcn_s_setprio(1);
        #pragma unroll
        for (int n = 0; n < 2; ++n) {
            #pragma unroll
            for (int ii = 0; ii < 16; ++ii) sacc[n][ii] = 0.f;
            #pragma unroll
            for (int ks = 0; ks < 4; ++ks) {
                half8 kf = *(const half8*)&kst[cur*(2*TILE_H) + (32*n + lq)*64 + ((16*ks + 8*h) ^ ksw)];
                sacc[n] = __builtin_amdgcn_mfma_f32_32x32x16_f16(kf, qf[ks], sacc[n], 0, 0, 0);
            }
        }
        __builtin_amdgcn_s_setprio(0);

        // ---- online softmax (exp2 domain, defer-max): q=lq lane-local ----
        float t16[16], t8[8], t4[4], t2[2];
        #pragma unroll
        for (int ii = 0; ii < 16; ++ii) t16[ii] = fmaxf(sacc[0][ii], sacc[1][ii]);
        #pragma unroll
        for (int ii = 0; ii < 8; ++ii) t8[ii] = fmaxf(t16[ii], t16[ii+8]);
        #pragma unroll
        for (int ii = 0; ii < 4; ++ii) t4[ii] = fmaxf(t8[ii], t8[ii+4]);
        t2[0] = fmaxf(t4[0], t4[2]); t2[1] = fmaxf(t4[1], t4[3]);
        float mx = fmaxf(t2[0], t2[1]);
        mx = fmaxf(mx, __shfl_xor(mx, 32, 64));

        const unsigned long long grow = __ballot(mx - m_run > 8.0f);
        if (grow != 0ull) {
            const float mnew = fmaxf(m_run, mx);
            const float alpha = fexp2(m_run - mnew);
            m_run = mnew;
            #pragma unroll
            for (int dm = 0; dm < 2; ++dm)
                #pragma unroll
                for (int ii = 0; ii < 16; ++ii) accO[dm][ii] *= alpha;
            l_run *= alpha;
        }
        #pragma unroll
        for (int n = 0; n < 2; ++n)
            #pragma unroll
            for (int ii = 0; ii < 16; ++ii) sacc[n][ii] = fexp2(sacc[n][ii] - m_run);
        {
            float a16[16], a8[8], a4[4];
            #pragma unroll
            for (int ii = 0; ii < 16; ++ii) a16[ii] = sacc[0][ii] + sacc[1][ii];
            #pragma unroll
            for (int ii = 0; ii < 8; ++ii) a8[ii] = a16[ii] + a16[ii+8];
            #pragma unroll
            for (int ii = 0; ii < 4; ++ii) a4[ii] = a8[ii] + a8[ii+4];
            l_run += (a4[0] + a4[1]) + (a4[2] + a4[3]);
        }

        // pack P to f16 word pairs
        u32 c[2][4][2];
        #pragma unroll
        for (int n = 0; n < 2; ++n)
            #pragma unroll
            for (int b = 0; b < 4; ++b)
                #pragma unroll
                for (int rp = 0; rp < 2; ++rp)
                    c[n][b][rp] = cvt2(sacc[n][4*b+2*rp], sacc[n][4*b+2*rp+1]);

        // ---- P^T B-fragments via lane<->lane+32 exchange (no LDS) ----
        half8 pb[4];
        #pragma unroll
        for (int ks2 = 0; ks2 < 4; ++ks2) {
            const int n = ks2 >> 1, k1 = ks2 & 1;
            union { u32 w[4]; half8 hh; } pu;
            #pragma unroll
            for (int rp = 0; rp < 2; ++rp) {
                const u32 lo = c[n][2*k1][rp], hi = c[n][2*k1+1][rp];
                const u32 keep = h ? hi : lo;
                const u32 send = h ? lo : hi;
                const u32 other = (u32)__shfl_xor((int)send, 32, 64);
                pu.w[rp]   = h ? other : keep;
                pu.w[2+rp] = h ? keep  : other;
            }
            pb[ks2] = pu.hh;
        }

        // ---- O^T += V^T · P^T : V via hardware transpose reads ----
        const u32 vb = vbase0 + (u32)(cur * (2 * TILE_H * 2));   // byte offset of buffer
        half4v t000,t001,t010,t011,t100,t101,t110,t111,
               t200,t201,t210,t211,t300,t301,t310,t311;
        #define TRR(dst, IMM) \
            asm volatile("ds_read_b64_tr_b16 %0, %1 offset:" #IMM : "=v"(dst) : "v"(vb) : "memory")
        TRR(t000,    0); TRR(t001, 1024); TRR(t010,  512); TRR(t011, 1536);
        TRR(t100, 2048); TRR(t101, 3072); TRR(t110, 2560); TRR(t111, 3584);
        TRR(t200, 4096); TRR(t201, 5120); TRR(t210, 4608); TRR(t211, 5632);
        TRR(t300, 6144); TRR(t301, 7168); TRR(t310, 6656); TRR(t311, 7680);
        #undef TRR
        asm volatile("s_waitcnt lgkmcnt(0)" ::: "memory");
        __builtin_amdgcn_sched_barrier(0);

        __builtin_amdgcn_s_setprio(1);
        #define PVM(ks, dm, ta, tb) { half8 vv;                                   \
            vv[0]=ta[0]; vv[1]=ta[1]; vv[2]=ta[2]; vv[3]=ta[3];                    \
            vv[4]=tb[0]; vv[5]=tb[1]; vv[6]=tb[2]; vv[7]=tb[3];                    \
            accO[dm] = __builtin_amdgcn_mfma_f32_32x32x16_f16(vv, pb[ks], accO[dm], 0, 0, 0); }
        PVM(0,0,t000,t001) PVM(0,1,t010,t011)
        PVM(1,0,t100,t101) PVM(1,1,t110,t111)
        PVM(2,0,t200,t201) PVM(2,1,t210,t211)
        PVM(3,0,t300,t301) PVM(3,1,t310,t311)
        #undef PVM
        __builtin_amdgcn_s_setprio(0);
    }
    #undef LOADKV
    #undef STAGE

    // ---- merge the two KV-group partials, then store ----
    const float ltot = l_run + __shfl_xor(l_run, 32, 64);

    float* mbuf = (float*)&smem[0][0][0][0];   // [34][4 waves][64 lanes]
    const int li = wv * 64 + lane;

    __syncthreads();   // all compute reads of smem done
    if (g == 1) {
        #pragma unroll
        for (int dm = 0; dm < 2; ++dm)
            #pragma unroll
            for (int ii = 0; ii < 16; ++ii)
                mbuf[(dm*16 + ii)*256 + li] = accO[dm][ii];
        mbuf[32*256 + li] = m_run;
        mbuf[33*256 + li] = ltot;
    }
    __syncthreads();
    if (g == 0) {
        const float mB = mbuf[32*256 + li];
        const float lB = mbuf[33*256 + li];
        const float m  = fmaxf(m_run, mB);
        const float a  = fexp2(m_run - m);
        const float b2 = fexp2(mB - m);
        const float inv = 1.0f / (ltot * a + lB * b2);
        float* orow = Og + hbase + (size_t)(q0 + lq) * DHEAD;
        #pragma unroll
        for (int dm = 0; dm < 2; ++dm)
            #pragma unroll
            for (int bb = 0; bb < 4; ++bb) {
                float4 o;
                #pragma unroll
                for (int jj = 0; jj < 4; ++jj) {
                    const float oA = accO[dm][4*bb+jj];
                    const float oB = mbuf[(dm*16 + 4*bb + jj)*256 + li];
                    ((float*)&o)[jj] = (oA * a + oB * b2) * inv;
                }
                *(float4*)(orow + 32*dm + 8*bb + 4*h) = o;
            }
    }
}

extern "C" void kernel_launch(void* const* d_in, const int* in_sizes, int n_in,
                              void* d_out, int out_size, void* d_ws, size_t ws_size,
                              hipStream_t stream) {
    const float* Q = (const float*)d_in[0];
    const float* K = (const float*)d_in[1];
    const float* V = (const float*)d_in[2];
    float* O = (float*)d_out;
    dim3 grid(32 * (SEQ / QBLK));   // 32 heads * 16 q-blocks = 512
    fattn_fwd<<<grid, 512, 0, stream>>>(Q, K, V, O);
}

// Round 6
// 70.943 us; speedup vs baseline: 1.3547x; 1.3547x over previous
//
#include <hip/hip_runtime.h>

#define SEQ   2048
#define DHEAD 64
#define QBLK  128
#define KVBLK 64
#define NT    (SEQ / KVBLK)      // 32 tiles
#define NI    (NT / 2)           // 16 tiles per KV-group
#define TILE_H (KVBLK * DHEAD)   // halves per K or V tile (4096 = 8KB)

typedef _Float16 half4v __attribute__((ext_vector_type(4)));
typedef _Float16 half8  __attribute__((ext_vector_type(8)));
typedef float    f32x16 __attribute__((ext_vector_type(16)));
typedef unsigned u32;

__device__ __forceinline__ u32 cvt2(float x, float y) {
    return __builtin_bit_cast(u32, __builtin_amdgcn_cvt_pkrtz(x, y));
}

__device__ __forceinline__ half8 pack8(float4 a, float4 b) {
    union { u32 w[4]; half8 h; } r;
    r.w[0] = cvt2(a.x, a.y);
    r.w[1] = cvt2(a.z, a.w);
    r.w[2] = cvt2(b.x, b.y);
    r.w[3] = cvt2(b.z, b.w);
    return r.h;
}

__device__ __forceinline__ float fexp2(float x) {
#if __has_builtin(__builtin_amdgcn_exp2f)
    return __builtin_amdgcn_exp2f(x);
#else
    return exp2f(x);
#endif
}

__global__ __launch_bounds__(512, 2)   // VGPR cap 128: 4 waves/SIMD, no spills
void fattn_fwd(const float* __restrict__ Qg, const float* __restrict__ Kg,
               const float* __restrict__ Vg, float* __restrict__ Og)
{
    // [group][buf][K=0/V=1][tile]  = 64 KB total; merge buffer reuses this space
    __shared__ __align__(16) _Float16 smem[2][2][2][TILE_H];

    const int tid  = threadIdx.x;
    const int wave = tid >> 6;
    const int lane = tid & 63;
    const int lq   = lane & 31;   // q fragment index
    const int h    = lane >> 5;   // k-half of the wave
    const int g    = wave >> 2;   // KV parity group
    const int wv   = wave & 3;    // q sub-tile
    const int gtid = tid & 255;   // thread id within group

    // XCD-bijective swizzle: 512 blocks, 64 per XCD = 4 whole heads per XCD
    const int bid = blockIdx.x;
    const int swz = (bid & 7) * 64 + (bid >> 3);
    const int head = swz >> 4;                  // 16 q-blocks per head
    const int qb   = swz & 15;
    const size_t hbase = (size_t)head * (SEQ * DHEAD);
    const int q0 = qb * QBLK + wv * 32;

    // ---- Q B-fragments, pre-scaled by log2e/sqrt(D) (exp2-domain softmax) ----
    half8 qf[4];
    {
        const float* qrow = Qg + hbase + (size_t)(q0 + lq) * DHEAD;
        const float sc = 0.125f * 1.44269504088896f;
        #pragma unroll
        for (int ks = 0; ks < 4; ++ks) {
            float4 a = *(const float4*)(qrow + 16*ks + 8*h);
            float4 b = *(const float4*)(qrow + 16*ks + 8*h + 4);
            a.x*=sc; a.y*=sc; a.z*=sc; a.w*=sc;
            b.x*=sc; b.y*=sc; b.z*=sc; b.w*=sc;
            qf[ks] = pack8(a, b);
        }
    }

    f32x16 accO[2];
    #pragma unroll
    for (int dm = 0; dm < 2; ++dm)
        #pragma unroll
        for (int i = 0; i < 16; ++i) accO[dm][i] = 0.f;
    float m_run = -1e30f, l_run = 0.f;

    // ---- staging mapping: group-thread -> (kv row, 16-float d-group) ----
    const int srow = gtid >> 2;
    const int scg  = gtid & 3;
    // group g handles tiles T = 2i+g
    const float* kgg = Kg + hbase + (size_t)srow * DHEAD + scg * 16 + (size_t)g * TILE_H;
    const float* vgg = Vg + hbase + (size_t)srow * DHEAD + scg * 16 + (size_t)g * TILE_H;
    const int kwo0 = srow*64 + (((2*scg)   ^ (srow & 7)) << 3);
    const int kwo1 = srow*64 + (((2*scg+1) ^ (srow & 7)) << 3);
    const int kv4  = srow >> 2;
    const int psub = 16*(kv4>>2) + 8*(kv4&1) + 4*(scg>>1) + 2*((kv4>>1)&1) + (scg&1);
    const int vwo0 = psub*64 + (srow & 3)*16;

    _Float16* kst = &smem[g][0][0][0];   // buf stride = 2*TILE_H halves
    _Float16* vst = &smem[g][0][1][0];

    const int ksw = (lq & 7) << 3;
    const u32 vbase0 = (u32)(size_t)vst + (u32)lane * 8u;

    float4 kr0,kr1,kr2,kr3, vr0,vr1,vr2,vr3;
    #define LOADKV(I) {                                                        \
        const float* kp = kgg + (size_t)(I) * (2 * TILE_H);                     \
        const float* vp = vgg + (size_t)(I) * (2 * TILE_H);                     \
        kr0 = *(const float4*)(kp+0); kr1 = *(const float4*)(kp+4);             \
        kr2 = *(const float4*)(kp+8); kr3 = *(const float4*)(kp+12);            \
        vr0 = *(const float4*)(vp+0); vr1 = *(const float4*)(vp+4);             \
        vr2 = *(const float4*)(vp+8); vr3 = *(const float4*)(vp+12); }
    #define STAGE(B) {                                                         \
        *(half8*)&kst[(B)*(2*TILE_H) + kwo0]     = pack8(kr0, kr1);             \
        *(half8*)&kst[(B)*(2*TILE_H) + kwo1]     = pack8(kr2, kr3);             \
        *(half8*)&vst[(B)*(2*TILE_H) + vwo0]     = pack8(vr0, vr1);             \
        *(half8*)&vst[(B)*(2*TILE_H) + vwo0 + 8] = pack8(vr2, vr3); }

    LOADKV(0); STAGE(0);
    LOADKV(1);

    #pragma unroll 1
    for (int i = 0; i < NI; ++i) {
        const int cur = i & 1;
        __syncthreads();   // tile staged; prior readers of buf[cur^1] done
        if (i + 1 < NI) STAGE(cur ^ 1);
        if (i + 2 < NI) LOADKV(i + 2);

        // ---- S^T = K · Q^T : 2 kv m-tiles x 4 k-steps ----
        f32x16 sacc[2];
        __builtin_amdgcn_s_setprio(1);
        #pragma unroll
        for (int n = 0; n < 2; ++n) {
            #pragma unroll
            for (int ii = 0; ii < 16; ++ii) sacc[n][ii] = 0.f;
            #pragma unroll
            for (int ks = 0; ks < 4; ++ks) {
                half8 kf = *(const half8*)&kst[cur*(2*TILE_H) + (32*n + lq)*64 + ((16*ks + 8*h) ^ ksw)];
                sacc[n] = __builtin_amdgcn_mfma_f32_32x32x16_f16(kf, qf[ks], sacc[n], 0, 0, 0);
            }
        }
        __builtin_amdgcn_s_setprio(0);

        // ---- online softmax (exp2 domain, defer-max): q=lq lane-local ----
        float t16[16], t8[8], t4[4], t2[2];
        #pragma unroll
        for (int ii = 0; ii < 16; ++ii) t16[ii] = fmaxf(sacc[0][ii], sacc[1][ii]);
        #pragma unroll
        for (int ii = 0; ii < 8; ++ii) t8[ii] = fmaxf(t16[ii], t16[ii+8]);
        #pragma unroll
        for (int ii = 0; ii < 4; ++ii) t4[ii] = fmaxf(t8[ii], t8[ii+4]);
        t2[0] = fmaxf(t4[0], t4[2]); t2[1] = fmaxf(t4[1], t4[3]);
        float mx = fmaxf(t2[0], t2[1]);
        mx = fmaxf(mx, __shfl_xor(mx, 32, 64));

        const unsigned long long grow = __ballot(mx - m_run > 8.0f);
        if (grow != 0ull) {
            const float mnew = fmaxf(m_run, mx);
            const float alpha = fexp2(m_run - mnew);
            m_run = mnew;
            #pragma unroll
            for (int dm = 0; dm < 2; ++dm)
                #pragma unroll
                for (int ii = 0; ii < 16; ++ii) accO[dm][ii] *= alpha;
            l_run *= alpha;
        }
        #pragma unroll
        for (int n = 0; n < 2; ++n)
            #pragma unroll
            for (int ii = 0; ii < 16; ++ii) sacc[n][ii] = fexp2(sacc[n][ii] - m_run);
        {
            float a16[16], a8[8], a4[4];
            #pragma unroll
            for (int ii = 0; ii < 16; ++ii) a16[ii] = sacc[0][ii] + sacc[1][ii];
            #pragma unroll
            for (int ii = 0; ii < 8; ++ii) a8[ii] = a16[ii] + a16[ii+8];
            #pragma unroll
            for (int ii = 0; ii < 4; ++ii) a4[ii] = a8[ii] + a8[ii+4];
            l_run += (a4[0] + a4[1]) + (a4[2] + a4[3]);
        }

        // pack P to f16 word pairs
        u32 c[2][4][2];
        #pragma unroll
        for (int n = 0; n < 2; ++n)
            #pragma unroll
            for (int b = 0; b < 4; ++b)
                #pragma unroll
                for (int rp = 0; rp < 2; ++rp)
                    c[n][b][rp] = cvt2(sacc[n][4*b+2*rp], sacc[n][4*b+2*rp+1]);

        // ---- P^T B-fragments via lane<->lane+32 exchange (no LDS) ----
        half8 pb[4];
        #pragma unroll
        for (int ks2 = 0; ks2 < 4; ++ks2) {
            const int n = ks2 >> 1, k1 = ks2 & 1;
            union { u32 w[4]; half8 hh; } pu;
            #pragma unroll
            for (int rp = 0; rp < 2; ++rp) {
                const u32 lo = c[n][2*k1][rp], hi = c[n][2*k1+1][rp];
                const u32 keep = h ? hi : lo;
                const u32 send = h ? lo : hi;
                const u32 other = (u32)__shfl_xor((int)send, 32, 64);
                pu.w[rp]   = h ? other : keep;
                pu.w[2+rp] = h ? keep  : other;
            }
            pb[ks2] = pu.hh;
        }

        // ---- O^T += V^T · P^T : V via hardware transpose reads ----
        const u32 vb = vbase0 + (u32)(cur * (2 * TILE_H * 2));   // byte offset of buffer
        half4v t000,t001,t010,t011,t100,t101,t110,t111,
               t200,t201,t210,t211,t300,t301,t310,t311;
        #define TRR(dst, IMM) \
            asm volatile("ds_read_b64_tr_b16 %0, %1 offset:" #IMM : "=v"(dst) : "v"(vb) : "memory")
        TRR(t000,    0); TRR(t001, 1024); TRR(t010,  512); TRR(t011, 1536);
        TRR(t100, 2048); TRR(t101, 3072); TRR(t110, 2560); TRR(t111, 3584);
        TRR(t200, 4096); TRR(t201, 5120); TRR(t210, 4608); TRR(t211, 5632);
        TRR(t300, 6144); TRR(t301, 7168); TRR(t310, 6656); TRR(t311, 7680);
        #undef TRR
        asm volatile("s_waitcnt lgkmcnt(0)" ::: "memory");
        __builtin_amdgcn_sched_barrier(0);

        __builtin_amdgcn_s_setprio(1);
        #define PVM(ks, dm, ta, tb) { half8 vv;                                   \
            vv[0]=ta[0]; vv[1]=ta[1]; vv[2]=ta[2]; vv[3]=ta[3];                    \
            vv[4]=tb[0]; vv[5]=tb[1]; vv[6]=tb[2]; vv[7]=tb[3];                    \
            accO[dm] = __builtin_amdgcn_mfma_f32_32x32x16_f16(vv, pb[ks], accO[dm], 0, 0, 0); }
        PVM(0,0,t000,t001) PVM(0,1,t010,t011)
        PVM(1,0,t100,t101) PVM(1,1,t110,t111)
        PVM(2,0,t200,t201) PVM(2,1,t210,t211)
        PVM(3,0,t300,t301) PVM(3,1,t310,t311)
        #undef PVM
        __builtin_amdgcn_s_setprio(0);
    }
    #undef LOADKV
    #undef STAGE

    // ---- merge the two KV-group partials, then store ----
    const float ltot = l_run + __shfl_xor(l_run, 32, 64);

    float* mbuf = (float*)&smem[0][0][0][0];   // [34][4 waves][64 lanes]
    const int li = wv * 64 + lane;

    __syncthreads();   // all compute reads of smem done
    if (g == 1) {
        #pragma unroll
        for (int dm = 0; dm < 2; ++dm)
            #pragma unroll
            for (int ii = 0; ii < 16; ++ii)
                mbuf[(dm*16 + ii)*256 + li] = accO[dm][ii];
        mbuf[32*256 + li] = m_run;
        mbuf[33*256 + li] = ltot;
    }
    __syncthreads();
    if (g == 0) {
        const float mB = mbuf[32*256 + li];
        const float lB = mbuf[33*256 + li];
        const float m  = fmaxf(m_run, mB);
        const float a  = fexp2(m_run - m);
        const float b2 = fexp2(mB - m);
        const float inv = 1.0f / (ltot * a + lB * b2);
        float* orow = Og + hbase + (size_t)(q0 + lq) * DHEAD;
        #pragma unroll
        for (int dm = 0; dm < 2; ++dm)
            #pragma unroll
            for (int bb = 0; bb < 4; ++bb) {
                float4 o;
                #pragma unroll
                for (int jj = 0; jj < 4; ++jj) {
                    const float oA = accO[dm][4*bb+jj];
                    const float oB = mbuf[(dm*16 + 4*bb + jj)*256 + li];
                    ((float*)&o)[jj] = (oA * a + oB * b2) * inv;
                }
                *(float4*)(orow + 32*dm + 8*bb + 4*h) = o;
            }
    }
}

extern "C" void kernel_launch(void* const* d_in, const int* in_sizes, int n_in,
                              void* d_out, int out_size, void* d_ws, size_t ws_size,
                              hipStream_t stream) {
    const float* Q = (const float*)d_in[0];
    const float* K = (const float*)d_in[1];
    const float* V = (const float*)d_in[2];
    float* O = (float*)d_out;
    dim3 grid(32 * (SEQ / QBLK));   // 32 heads * 16 q-blocks = 512
    fattn_fwd<<<grid, 512, 0, stream>>>(Q, K, V, O);
}

// Round 8
// 67.794 us; speedup vs baseline: 1.4176x; 1.0464x over previous
//
#include <hip/hip_runtime.h>

#define SEQ   2048
#define DHEAD 64
#define QBLK  128
#define KVBLK 64
#define NT    (SEQ / KVBLK)      // 32 tiles
#define TILE_H (KVBLK * DHEAD)   // halves per K or V tile (4096 = 8KB)

typedef _Float16 half4v __attribute__((ext_vector_type(4)));
typedef _Float16 half8  __attribute__((ext_vector_type(8)));
typedef float    f32x16 __attribute__((ext_vector_type(16)));
typedef unsigned u32;

__device__ __forceinline__ u32 cvt2(float x, float y) {
    return __builtin_bit_cast(u32, __builtin_amdgcn_cvt_pkrtz(x, y));
}

__device__ __forceinline__ half8 pack8(float4 a, float4 b) {
    union { u32 w[4]; half8 h; } r;
    r.w[0] = cvt2(a.x, a.y);
    r.w[1] = cvt2(a.z, a.w);
    r.w[2] = cvt2(b.x, b.y);
    r.w[3] = cvt2(b.z, b.w);
    return r.h;
}

__device__ __forceinline__ float fexp2(float x) {
#if __has_builtin(__builtin_amdgcn_exp2f)
    return __builtin_amdgcn_exp2f(x);
#else
    return exp2f(x);
#endif
}

__global__ __launch_bounds__(256, 2)
void fattn_fwd(const float* __restrict__ Qg, const float* __restrict__ Kg,
               const float* __restrict__ Vg, float* __restrict__ Og)
{
    // [buf(3)][K=0/V=1][tile]  = 48 KB; triple-buffered pipeline
    __shared__ __align__(16) _Float16 smem[3][2][TILE_H];

    const int tid  = threadIdx.x;
    const int wave = tid >> 6;
    const int lane = tid & 63;
    const int lq   = lane & 31;   // q fragment index
    const int h    = lane >> 5;   // k-half of the wave

    // XCD-bijective swizzle: 512 blocks, 64 per XCD = 4 whole heads per XCD
    const int bid = blockIdx.x;
    const int swz = (bid & 7) * 64 + (bid >> 3);
    const int head = swz >> 4;                  // 16 q-blocks per head
    const int qb   = swz & 15;
    const size_t hbase = (size_t)head * (SEQ * DHEAD);
    const int q0 = qb * QBLK + wave * 32;

    // ---- Q B-fragments, pre-scaled by log2e/sqrt(D) (exp2-domain softmax) ----
    half8 qf[4];
    {
        const float* qrow = Qg + hbase + (size_t)(q0 + lq) * DHEAD;
        const float sc = 0.125f * 1.44269504088896f;
        #pragma unroll
        for (int ks = 0; ks < 4; ++ks) {
            float4 a = *(const float4*)(qrow + 16*ks + 8*h);
            float4 b = *(const float4*)(qrow + 16*ks + 8*h + 4);
            a.x*=sc; a.y*=sc; a.z*=sc; a.w*=sc;
            b.x*=sc; b.y*=sc; b.z*=sc; b.w*=sc;
            qf[ks] = pack8(a, b);
        }
    }

    f32x16 accO[2];
    #pragma unroll
    for (int dm = 0; dm < 2; ++dm)
        #pragma unroll
        for (int i = 0; i < 16; ++i) accO[dm][i] = 0.f;
    float m_run = -1e30f, l_run = 0.f;

    // ---- staging mapping: thread -> (kv row, 16-float d-group) ----
    const int srow = tid >> 2;
    const int scg  = tid & 3;
    const float* kgg = Kg + hbase + (size_t)srow * DHEAD + scg * 16;
    const float* vgg = Vg + hbase + (size_t)srow * DHEAD + scg * 16;
    const int kwo0 = srow*64 + (((2*scg)   ^ (srow & 7)) << 3);
    const int kwo1 = srow*64 + (((2*scg+1) ^ (srow & 7)) << 3);
    const int kv4  = srow >> 2;
    const int psub = 16*(kv4>>2) + 8*(kv4&1) + 4*(scg>>1) + 2*((kv4>>1)&1) + (scg&1);
    const int vwo0 = psub*64 + (srow & 3)*16;

    const int ksw = (lq & 7) << 3;
    const u32 vbyte0 = (u32)(size_t)(&smem[0][1][0]) + (u32)lane * 8u;

    float4 kr0,kr1,kr2,kr3, vr0,vr1,vr2,vr3;
    #define LOADKV(T) {                                                        \
        const float* kp = kgg + (size_t)(T) * TILE_H;                           \
        const float* vp = vgg + (size_t)(T) * TILE_H;                           \
        kr0 = *(const float4*)(kp+0); kr1 = *(const float4*)(kp+4);             \
        kr2 = *(const float4*)(kp+8); kr3 = *(const float4*)(kp+12);            \
        vr0 = *(const float4*)(vp+0); vr1 = *(const float4*)(vp+4);             \
        vr2 = *(const float4*)(vp+8); vr3 = *(const float4*)(vp+12); }
    #define STAGE(B) {                                                         \
        *(half8*)&smem[B][0][kwo0]     = pack8(kr0, kr1);                       \
        *(half8*)&smem[B][0][kwo1]     = pack8(kr2, kr3);                       \
        *(half8*)&smem[B][1][vwo0]     = pack8(vr0, vr1);                       \
        *(half8*)&smem[B][1][vwo0 + 8] = pack8(vr2, vr3); }

    // ---- prologue: stage tiles 0,1; QK(0) ----
    LOADKV(0); STAGE(0);
    LOADKV(1);
    __syncthreads();
    STAGE(1);
    LOADKV(2);

    f32x16 saccA[2], saccB[2];
    {   // QK(0) from buf0
        #pragma unroll
        for (int n = 0; n < 2; ++n) {
            #pragma unroll
            for (int ii = 0; ii < 16; ++ii) saccA[n][ii] = 0.f;
            #pragma unroll
            for (int ks = 0; ks < 4; ++ks) {
                half8 kf = *(const half8*)&smem[0][0][(32*n + lq)*64 + ((16*ks + 8*h) ^ ksw)];
                saccA[n] = __builtin_amdgcn_mfma_f32_32x32x16_f16(kf, qf[ks], saccA[n], 0, 0, 0);
            }
        }
    }

    int t = 0, bP = 0, bQ = 1, bS = 2;

    // one sub-iteration: softmax+PV on tile t (sacc=SC), QK of t+1 into SN
    auto subiter = [&](f32x16 (&SC)[2], f32x16 (&SN)[2]) {
        __syncthreads();   // buf[bQ] (staged last iter) visible; buf[bS] free to overwrite
        if (t + 2 < NT) STAGE(bS);
        if (t + 3 < NT) LOADKV(t + 3);

        // ---- online softmax (exp2 domain, defer-max) on SC ----
        {
            float t16[16], t8[8], t4[4];
            #pragma unroll
            for (int ii = 0; ii < 16; ++ii) t16[ii] = fmaxf(SC[0][ii], SC[1][ii]);
            #pragma unroll
            for (int ii = 0; ii < 8; ++ii) t8[ii] = fmaxf(t16[ii], t16[ii+8]);
            #pragma unroll
            for (int ii = 0; ii < 4; ++ii) t4[ii] = fmaxf(t8[ii], t8[ii+4]);
            float mx = fmaxf(fmaxf(t4[0], t4[2]), fmaxf(t4[1], t4[3]));
            mx = fmaxf(mx, __shfl_xor(mx, 32, 64));

            const unsigned long long grow = __ballot(mx - m_run > 8.0f);
            if (grow != 0ull) {
                const float mnew = fmaxf(m_run, mx);
                const float alpha = fexp2(m_run - mnew);
                m_run = mnew;
                #pragma unroll
                for (int dm = 0; dm < 2; ++dm)
                    #pragma unroll
                    for (int ii = 0; ii < 16; ++ii) accO[dm][ii] *= alpha;
                l_run *= alpha;
            }
        }
        #pragma unroll
        for (int n = 0; n < 2; ++n)
            #pragma unroll
            for (int ii = 0; ii < 16; ++ii) SC[n][ii] = fexp2(SC[n][ii] - m_run);
        {
            float a16[16], a8[8], a4[4];
            #pragma unroll
            for (int ii = 0; ii < 16; ++ii) a16[ii] = SC[0][ii] + SC[1][ii];
            #pragma unroll
            for (int ii = 0; ii < 8; ++ii) a8[ii] = a16[ii] + a16[ii+8];
            #pragma unroll
            for (int ii = 0; ii < 4; ++ii) a4[ii] = a8[ii] + a8[ii+4];
            l_run += (a4[0] + a4[1]) + (a4[2] + a4[3]);
        }

        // ---- pack P to f16 + lane<->lane+32 exchange (verified shfl pattern) ----
        half8 pb[4];
        #pragma unroll
        for (int ks2 = 0; ks2 < 4; ++ks2) {
            const int n = ks2 >> 1, k1 = ks2 & 1;
            union { u32 w[4]; half8 hh; } pu;
            #pragma unroll
            for (int rp = 0; rp < 2; ++rp) {
                const u32 lo = cvt2(SC[n][4*(2*k1)  +2*rp], SC[n][4*(2*k1)  +2*rp+1]);
                const u32 hi = cvt2(SC[n][4*(2*k1+1)+2*rp], SC[n][4*(2*k1+1)+2*rp+1]);
                const u32 keep = h ? hi : lo;
                const u32 send = h ? lo : hi;
                const u32 other = (u32)__shfl_xor((int)send, 32, 64);
                pu.w[rp]   = h ? other : keep;   // slots for k-half 0
                pu.w[2+rp] = h ? keep  : other;  // slots for k-half 1
            }
            pb[ks2] = pu.hh;
        }

        // ---- QK(t+1) into SN (independent: overlaps softmax above) ----
        if (t + 1 < NT) {
            const _Float16* kb_ = &smem[bQ][0][0];
            #pragma unroll
            for (int n = 0; n < 2; ++n) {
                #pragma unroll
                for (int ii = 0; ii < 16; ++ii) SN[n][ii] = 0.f;
                #pragma unroll
                for (int ks = 0; ks < 4; ++ks) {
                    half8 kf = *(const half8*)&kb_[(32*n + lq)*64 + ((16*ks + 8*h) ^ ksw)];
                    SN[n] = __builtin_amdgcn_mfma_f32_32x32x16_f16(kf, qf[ks], SN[n], 0, 0, 0);
                }
            }
        }

        // ---- O^T += V^T · P^T : V via hardware transpose reads (buf bP) ----
        const u32 vb = vbyte0 + (u32)bP * (u32)(4 * TILE_H);   // 16 KB per buf
        half4v t000,t001,t010,t011,t100,t101,t110,t111,
               t200,t201,t210,t211,t300,t301,t310,t311;
        #define TRR(dst, IMM) \
            asm volatile("ds_read_b64_tr_b16 %0, %1 offset:" #IMM : "=v"(dst) : "v"(vb) : "memory")
        TRR(t000,    0); TRR(t001, 1024); TRR(t010,  512); TRR(t011, 1536);
        TRR(t100, 2048); TRR(t101, 3072); TRR(t110, 2560); TRR(t111, 3584);
        TRR(t200, 4096); TRR(t201, 5120); TRR(t210, 4608); TRR(t211, 5632);
        TRR(t300, 6144); TRR(t301, 7168); TRR(t310, 6656); TRR(t311, 7680);
        #undef TRR
        asm volatile("s_waitcnt lgkmcnt(0)" ::: "memory");
        __builtin_amdgcn_sched_barrier(0);

        __builtin_amdgcn_s_setprio(1);
        #define PVM(ks, dm, ta, tb) { half8 vv;                                   \
            vv[0]=ta[0]; vv[1]=ta[1]; vv[2]=ta[2]; vv[3]=ta[3];                    \
            vv[4]=tb[0]; vv[5]=tb[1]; vv[6]=tb[2]; vv[7]=tb[3];                    \
            accO[dm] = __builtin_amdgcn_mfma_f32_32x32x16_f16(vv, pb[ks], accO[dm], 0, 0, 0); }
        PVM(0,0,t000,t001) PVM(0,1,t010,t011)
        PVM(1,0,t100,t101) PVM(1,1,t110,t111)
        PVM(2,0,t200,t201) PVM(2,1,t210,t211)
        PVM(3,0,t300,t301) PVM(3,1,t310,t311)
        #undef PVM
        __builtin_amdgcn_s_setprio(0);

        const int tmp = bP; bP = bQ; bQ = bS; bS = tmp; ++t;
    };

    #pragma unroll 1
    for (int it = 0; it < NT / 2; ++it) {
        subiter(saccA, saccB);
        subiter(saccB, saccA);
    }
    #undef LOADKV
    #undef STAGE

    // ---- epilogue ----
    const float ltot = l_run + __shfl_xor(l_run, 32, 64);
    const float inv = 1.0f / ltot;
    float* orow = Og + hbase + (size_t)(q0 + lq) * DHEAD;
    #pragma unroll
    for (int dm = 0; dm < 2; ++dm)
        #pragma unroll
        for (int bb = 0; bb < 4; ++bb) {
            float4 o;
            o.x = accO[dm][4*bb+0] * inv;
            o.y = accO[dm][4*bb+1] * inv;
            o.z = accO[dm][4*bb+2] * inv;
            o.w = accO[dm][4*bb+3] * inv;
            *(float4*)(orow + 32*dm + 8*bb + 4*h) = o;
        }
}

extern "C" void kernel_launch(void* const* d_in, const int* in_sizes, int n_in,
                              void* d_out, int out_size, void* d_ws, size_t ws_size,
                              hipStream_t stream) {
    const float* Q = (const float*)d_in[0];
    const float* K = (const float*)d_in[1];
    const float* V = (const float*)d_in[2];
    float* O = (float*)d_out;
    dim3 grid(32 * (SEQ / QBLK));   // 32 heads * 16 q-blocks = 512
    fattn_fwd<<<grid, 256, 0, stream>>>(Q, K, V, O);
}